// Round 6
// baseline (611.754 us; speedup 1.0000x reference)
//
#include <hip/hip_runtime.h>
#include <stdint.h>

typedef unsigned short u16;
typedef __attribute__((ext_vector_type(8))) __bf16 bf16x8;
typedef __attribute__((ext_vector_type(4))) float f32x4;

#define Dn 512
#define Mn 16384  // T*B rows
#define GRID_BLOCKS 1024u

// ---------- helpers ----------

__device__ __forceinline__ u16 f2bf(float f) {
  unsigned u = __float_as_uint(f);
  u += 0x7fffu + ((u >> 16) & 1u);
  return (u16)(u >> 16);
}

__device__ __forceinline__ float bf2f(u16 b) {
  return __uint_as_float(((unsigned)b) << 16);
}

__device__ __forceinline__ void async16(const u16* g, u16* l) {
  // global -> LDS direct copy, 16 B per lane. LDS dest = wave-uniform base + lane*16.
  __builtin_amdgcn_global_load_lds(
      (const __attribute__((address_space(1))) unsigned int*)g,
      (__attribute__((address_space(3))) unsigned int*)l, 16, 0, 0);
}

__device__ __forceinline__ float sigmoidf_(float v) {
  return 1.f / (1.f + __expf(-v));
}

// Hand-rolled grid barrier (graph-capture-safe; no cooperative launch).
// Requires all blocks co-resident: grid = 1024 = exactly 4 blocks/CU x 256 CU
// (LDS 32KB -> 5/CU cap; launch_bounds(256,4) -> regs<=128 -> 16 waves/CU; slots 8/CU).
// Agent-scope atomics hit the device-coherent point (works across per-XCD L2s);
// __threadfence() = agent-scope release/acquire (compiler emits wbl2/inv).
// Self-cleaning: cnt reset by last arriver BEFORE gen bump; gen monotone within a
// launch; both re-zeroed every graph replay by the captured hipMemsetAsync.
// Failsafe bounded spin (~0.4s) turns a residency bug into wrong-numerics, not a hang.
__device__ __forceinline__ void grid_barrier(unsigned* cnt, unsigned* gen) {
  __syncthreads();
  if (threadIdx.x == 0) {
    __threadfence();  // publish this block's writes device-wide
    unsigned g = __hip_atomic_load(gen, __ATOMIC_RELAXED, __HIP_MEMORY_SCOPE_AGENT);
    unsigned arrived = __hip_atomic_fetch_add(cnt, 1u, __ATOMIC_ACQ_REL, __HIP_MEMORY_SCOPE_AGENT);
    if (arrived == GRID_BLOCKS - 1u) {
      __hip_atomic_store(cnt, 0u, __ATOMIC_RELAXED, __HIP_MEMORY_SCOPE_AGENT);
      __hip_atomic_store(gen, g + 1u, __ATOMIC_RELEASE, __HIP_MEMORY_SCOPE_AGENT);
    } else {
      unsigned spins = 0;
      while (__hip_atomic_load(gen, __ATOMIC_ACQUIRE, __HIP_MEMORY_SCOPE_AGENT) == g) {
        __builtin_amdgcn_s_sleep(2);
        if (++spins > (1u << 23)) break;  // failsafe
      }
    }
    __threadfence();  // invalidate caches before consuming others' data
  }
  __syncthreads();
}

struct FArgs {
  const float *y, *x, *w0, *w1, *w2, *w3, *w4, *w5, *bg;
  u16 *yb, *xb, *rxb, *zb, *bRZ, *bG;
  float* out;
  unsigned *bar_cnt, *bar_gen;
};

// ---------- fused kernel: cast -> barrier -> rz -> barrier -> gu ----------
// Phase bodies byte-identical to the round-4 measured kernels (cast_all2 / gemm_rz1
// / gemm_gu2); the grid barrier replaces the two kernel boundaries.
__global__ __launch_bounds__(256, 4) void fused_gru(FArgs a) {
  __shared__ u16 smem[16384];  // 32 KB: rz uses all, gu uses first 24 KB
  const int tid = (int)threadIdx.x;

  // ================= phase 0: casts =================
  {
    const int stride = (int)gridDim.x * 256;
    for (int idx = (int)blockIdx.x * 256 + tid; idx < 17920 * 256; idx += stride) {
      int b = idx >> 8;
      const int t = idx & 255;
      if (b < 16384) {
        const float* src;
        u16* dst;
        if (b < 8192) { src = a.y; dst = a.yb; }
        else          { src = a.x; dst = a.xb; b -= 8192; }
        const int i4 = b * 256 + t;
        float4 v = ((const float4*)src)[i4];
        ushort4 o;
        o.x = f2bf(v.x); o.y = f2bf(v.y); o.z = f2bf(v.z); o.w = f2bf(v.w);
        ((ushort4*)dst)[i4] = o;
        continue;
      }
      b -= 16384;
      const int wi = b >> 8;  // 0..5 : Wr,Ur,Wz,Uz,Wg,Ug
      const int bb = b & 255;
      const float* src = wi == 0 ? a.w0 : wi == 1 ? a.w1 : wi == 2 ? a.w2
                       : wi == 3 ? a.w3 : wi == 4 ? a.w4 : a.w5;
      const int i4 = bb * 256 + t;        // float4 index within 512x512 weight
      const int e  = i4 >> 7;             // output row 0..511
      const int c4 = i4 & 127;            // float4 col within 512
      float4 v = ((const float4*)src)[i4];
      ushort4 o;
      o.x = f2bf(v.x); o.y = f2bf(v.y); o.z = f2bf(v.z); o.w = f2bf(v.w);
      ushort4* base = (wi >= 4) ? (ushort4*)a.bG : (ushort4*)a.bRZ;
      const int row = e + ((wi == 2 || wi == 3) ? 512 : 0);
      const int off = row * 256 + c4 + ((wi & 1) ? 128 : 0);
      base[off] = o;
    }
  }
  grid_barrier(a.bar_cnt, a.bar_gen);

  // ================= phase 1: rz  C=[y|x]@bRZ^T (M=16384,N=1024,K=1024) =================
  // 128x128 tile, BK=64, 4 waves (2x2). mb fast -> A-sharers same XCD.
  // XOR swizzle (0-conflict proven). Epilogue: nb<4 -> rx, else z.
  {
    u16* sA = smem;
    u16* sB = smem + 8192;

    const int lane = tid & 63;
    const int wave = tid >> 6;
    const int waveM = wave >> 1, waveN = wave & 1;
    const int mb = (int)blockIdx.x & 127, nb = (int)blockIdx.x >> 7;
    const int rowStart = mb * 128, colStart = nb * 128;
    const int wbyte = (tid & 192) * 16;
    const int lm = lane & 15, quad = lane >> 4;

    const int srow = tid >> 3;
    const int scol = (((tid & 7) ^ ((tid >> 3) & 7)) * 8);
    const int lswz = lm & 7;

    f32x4 acc[4][4] = {};

    for (int kq = 0; kq < 16; ++kq) {
      const int half = kq >> 3;
      const int k0 = (kq & 7) * 64;
      const u16* abase = half ? a.xb : a.yb;  // A = [y | x] along K
#pragma unroll
      for (int s = 0; s < 4; ++s) {
        async16(abase + (size_t)(rowStart + s * 32 + srow) * 512 + k0 + scol,
                (u16*)((char*)sA + s * 4096 + wbyte));
        async16(a.bRZ + (size_t)(colStart + s * 32 + srow) * 1024 + kq * 64 + scol,
                (u16*)((char*)sB + s * 4096 + wbyte));
      }
      __syncthreads();

#pragma unroll
      for (int kk = 0; kk < 2; ++kk) {
        bf16x8 aa[4], bw[4];
#pragma unroll
        for (int i = 0; i < 4; ++i)
          aa[i] = *(const bf16x8*)(sA + (waveM * 64 + i * 16 + lm) * 64 +
                                   ((kk * 4 + quad) ^ lswz) * 8);
#pragma unroll
        for (int j = 0; j < 4; ++j)
          bw[j] = *(const bf16x8*)(sB + (waveN * 64 + j * 16 + lm) * 64 +
                                   ((kk * 4 + quad) ^ lswz) * 8);
#pragma unroll
        for (int i = 0; i < 4; ++i)
#pragma unroll
          for (int j = 0; j < 4; ++j)
            acc[i][j] = __builtin_amdgcn_mfma_f32_16x16x32_bf16(aa[i], bw[j], acc[i][j], 0, 0, 0);
      }
      __syncthreads();
    }

    if (colStart < 512) {
      // R half: rx = bf16(sigmoid(acc) * x)
#pragma unroll
      for (int j = 0; j < 4; ++j) {
        const int e = colStart + waveN * 64 + j * 16 + lm;
#pragma unroll
        for (int i = 0; i < 4; ++i) {
          const int m0 = rowStart + waveM * 64 + i * 16 + quad * 4;
#pragma unroll
          for (int rg = 0; rg < 4; ++rg) {
            const size_t idx = (size_t)(m0 + rg) * 512 + e;
            const float r = sigmoidf_(acc[i][j][rg]);
            a.rxb[idx] = f2bf(r * bf2f(a.xb[idx]));
          }
        }
      }
    } else {
      // Z half: z = bf16(sigmoid(acc - bg))
#pragma unroll
      for (int j = 0; j < 4; ++j) {
        const int e = colStart - 512 + waveN * 64 + j * 16 + lm;
        const float bgv = a.bg[e];
#pragma unroll
        for (int i = 0; i < 4; ++i) {
          const int m0 = rowStart + waveM * 64 + i * 16 + quad * 4;
#pragma unroll
          for (int rg = 0; rg < 4; ++rg) {
            const size_t idx = (size_t)(m0 + rg) * 512 + e;
            a.zb[idx] = f2bf(sigmoidf_(acc[i][j][rg] - bgv));
          }
        }
      }
    }
  }
  grid_barrier(a.bar_cnt, a.bar_gen);

  // ================= phase 2: gu  accF=[y|rx]@bG^T (M=16384,N=512,K=1024) =================
  // 64x128 tile, BK=64, 256mb x 4nb. Epilogue: out = (1-z)x + z*tanh(accF).
  {
    u16* sA = smem;
    u16* sB = smem + 4096;

    const int lane = tid & 63;
    const int wave = tid >> 6;
    const int waveM = wave >> 1, waveN = wave & 1;
    const int mb = (int)blockIdx.x & 255, nb = (int)blockIdx.x >> 8;
    const int rowStart = mb * 64, colStart = nb * 128;
    const int wbyte = (tid & 192) * 16;
    const int lm = lane & 15, quad = lane >> 4;

    const int srow = tid >> 3;
    const int scol = (((tid & 7) ^ ((tid >> 3) & 7)) * 8);
    const int lswz = lm & 7;

    f32x4 acc[2][4] = {};

    for (int kq = 0; kq < 16; ++kq) {
      const int half = kq >> 3;
      const int k0 = (kq & 7) * 64;
      const u16* abase = half ? a.rxb : a.yb;  // A = [y | rx] along K
#pragma unroll
      for (int s = 0; s < 2; ++s)
        async16(abase + (size_t)(rowStart + s * 32 + srow) * 512 + k0 + scol,
                (u16*)((char*)sA + s * 4096 + wbyte));
#pragma unroll
      for (int s = 0; s < 4; ++s)
        async16(a.bG + (size_t)(colStart + s * 32 + srow) * 1024 + kq * 64 + scol,
                (u16*)((char*)sB + s * 4096 + wbyte));
      __syncthreads();

#pragma unroll
      for (int kk = 0; kk < 2; ++kk) {
        bf16x8 aa[2], bw[4];
#pragma unroll
        for (int i = 0; i < 2; ++i)
          aa[i] = *(const bf16x8*)(sA + (waveM * 32 + i * 16 + lm) * 64 +
                                   ((kk * 4 + quad) ^ lswz) * 8);
#pragma unroll
        for (int j = 0; j < 4; ++j)
          bw[j] = *(const bf16x8*)(sB + (waveN * 64 + j * 16 + lm) * 64 +
                                   ((kk * 4 + quad) ^ lswz) * 8);
#pragma unroll
        for (int i = 0; i < 2; ++i)
#pragma unroll
          for (int j = 0; j < 4; ++j)
            acc[i][j] = __builtin_amdgcn_mfma_f32_16x16x32_bf16(aa[i], bw[j], acc[i][j], 0, 0, 0);
      }
      __syncthreads();
    }

    // epilogue: out = (1-z)x + z*tanh(accF)
#pragma unroll
    for (int j = 0; j < 4; ++j) {
      const int e = colStart + waveN * 64 + j * 16 + lm;
#pragma unroll
      for (int i = 0; i < 2; ++i) {
        const int m0 = rowStart + waveM * 32 + i * 16 + quad * 4;
#pragma unroll
        for (int rg = 0; rg < 4; ++rg) {
          const size_t idx = (size_t)(m0 + rg) * 512 + e;
          const float pre = acc[i][j][rg];
          const float ex = __expf(-2.f * pre);
          const float h = (1.f - ex) / (1.f + ex);  // tanh
          const float z = bf2f(a.zb[idx]);
          const float xv = bf2f(a.xb[idx]);
          a.out[idx] = (1.f - z) * xv + z * h;
        }
      }
    }
  }
}

// ---------- launch ----------
extern "C" void kernel_launch(void* const* d_in, const int* in_sizes, int n_in,
                              void* d_out, int out_size, void* d_ws, size_t ws_size,
                              hipStream_t stream) {
  // ws layout (bytes): yb 16M | xb 16M | rxb 16M | zb 16M | bRZ 2M | bG 1M | bar 256B
  char* ws = (char*)d_ws;
  FArgs fa;
  fa.x  = (const float*)d_in[0];
  fa.y  = (const float*)d_in[1];
  fa.w0 = (const float*)d_in[2];  // Wr
  fa.w1 = (const float*)d_in[3];  // Ur
  fa.w2 = (const float*)d_in[4];  // Wz
  fa.w3 = (const float*)d_in[5];  // Uz
  fa.w4 = (const float*)d_in[6];  // Wg
  fa.w5 = (const float*)d_in[7];  // Ug
  fa.bg = (const float*)d_in[8];
  fa.yb  = (u16*)(ws);
  fa.xb  = (u16*)(ws + 16777216);
  fa.rxb = (u16*)(ws + 2 * 16777216);
  fa.zb  = (u16*)(ws + 3 * 16777216);
  fa.bRZ = (u16*)(ws + 4 * 16777216);
  fa.bG  = (u16*)(ws + 4 * 16777216 + 2097152);
  char* bar = ws + 4 * 16777216 + 2097152 + 1048576;
  fa.bar_cnt = (unsigned*)(bar);
  fa.bar_gen = (unsigned*)(bar + 128);
  fa.out = (float*)d_out;

  // Captured into the graph -> barrier state re-zeroed on every replay
  // (immune to workspace re-poisoning between iterations).
  hipMemsetAsync(bar, 0, 256, stream);
  fused_gru<<<dim3(GRID_BLOCKS), dim3(256), 0, stream>>>(fa);
}

// Round 7
// 233.929 us; speedup vs baseline: 2.6151x; 2.6151x over previous
//
#include <hip/hip_runtime.h>
#include <stdint.h>

typedef unsigned short u16;
typedef unsigned long long u64;
typedef __attribute__((ext_vector_type(8))) __bf16 bf16x8;
typedef __attribute__((ext_vector_type(4))) float f32x4;

#define Dn 512
#define Mn 16384  // T*B rows

// ---------- helpers ----------

__device__ __forceinline__ u16 f2bf(float f) {
  unsigned u = __float_as_uint(f);
  u += 0x7fffu + ((u >> 16) & 1u);
  return (u16)(u >> 16);
}

__device__ __forceinline__ float bf2f(u16 b) {
  return __uint_as_float(((unsigned)b) << 16);
}

__device__ __forceinline__ void async16(const u16* g, u16* l) {
  // global -> LDS direct copy, 16 B per lane. LDS dest = wave-uniform base + lane*16.
  __builtin_amdgcn_global_load_lds(
      (const __attribute__((address_space(1))) unsigned int*)g,
      (__attribute__((address_space(3))) unsigned int*)l, 16, 0, 0);
}

__device__ __forceinline__ float sigmoidf_(float v) {
  return 1.f / (1.f + __expf(-v));
}

// Agent-scope (device-coherent) accessors. Relaxed => no buffer_inv/wbl2 cache ops
// (round-6 lesson: acquire-spin's per-iteration buffer_inv storms kill the chip).
// Relaxed agent stores write through to the coherent point (sc0 sc1) -> visible
// cross-XCD after the producer's vmcnt drain; relaxed agent loads always read the
// coherent point -> also immune to stale consumer-L2 lines across graph replays.
__device__ __forceinline__ void st_u16_coh(u16* p, u16 v) {
  __hip_atomic_store(p, v, __ATOMIC_RELAXED, __HIP_MEMORY_SCOPE_AGENT);
}
__device__ __forceinline__ u16 ld_u16_coh(const u16* p) {
  return __hip_atomic_load(p, __ATOMIC_RELAXED, __HIP_MEMORY_SCOPE_AGENT);
}
__device__ __forceinline__ u64 ld_u64_coh(const u64* p) {
  return __hip_atomic_load(p, __ATOMIC_RELAXED, __HIP_MEMORY_SCOPE_AGENT);
}

// ---------- merged cast kernel (grid-stride, 2048 blocks) ----------
// work items 0..16383: y/x rows -> yb/xb ; 16384..17919: 6 weights -> concat:
//   bRZ (1024 x 1024 bf16): rows 0-511 = [Wr | Ur], rows 512-1023 = [Wz | Uz]
//   bG  ( 512 x 1024 bf16): rows 0-511 = [Wg | Ug]
__global__ void cast_all2(const float* __restrict__ y, const float* __restrict__ x,
                          const float* w0, const float* w1, const float* w2,
                          const float* w3, const float* w4, const float* w5,
                          u16* __restrict__ yb, u16* __restrict__ xb,
                          u16* __restrict__ bRZ, u16* __restrict__ bG) {
  const int stride = gridDim.x * 256;
  for (int idx = blockIdx.x * 256 + (int)threadIdx.x; idx < 17920 * 256; idx += stride) {
    int b = idx >> 8;
    const int t = idx & 255;
    if (b < 16384) {
      const float* src;
      u16* dst;
      if (b < 8192) { src = y; dst = yb; }
      else          { src = x; dst = xb; b -= 8192; }
      const int i4 = b * 256 + t;
      float4 v = ((const float4*)src)[i4];
      ushort4 o;
      o.x = f2bf(v.x); o.y = f2bf(v.y); o.z = f2bf(v.z); o.w = f2bf(v.w);
      ((ushort4*)dst)[i4] = o;
      continue;
    }
    b -= 16384;
    const int wi = b >> 8;  // 0..5 : Wr,Ur,Wz,Uz,Wg,Ug
    const int bb = b & 255;
    const float* src = wi == 0 ? w0 : wi == 1 ? w1 : wi == 2 ? w2
                     : wi == 3 ? w3 : wi == 4 ? w4 : w5;
    const int i4 = bb * 256 + t;        // float4 index within 512x512 weight
    const int e  = i4 >> 7;             // output row 0..511
    const int c4 = i4 & 127;            // float4 col within 512
    float4 v = ((const float4*)src)[i4];
    ushort4 o;
    o.x = f2bf(v.x); o.y = f2bf(v.y); o.z = f2bf(v.z); o.w = f2bf(v.w);
    ushort4* base = (wi >= 4) ? (ushort4*)bG : (ushort4*)bRZ;
    const int row = e + ((wi == 2 || wi == 3) ? 512 : 0);
    const int off = row * 256 + c4 + ((wi & 1) ? 128 : 0);  // 256 ushort4 per 1024-col row
    base[off] = o;
  }
}

struct GArgs {
  const u16 *yb, *xb, *bRZ, *bG;
  const float* bg;
  u16 *rxb, *zb;
  const u16 *rxb_c, *zb_c;  // const views for consumer
  float* out;
  unsigned* flags;  // 128 entries, one per rz mb; target count 8 (all nb)
};

// ---------- fused GEMM kernel: rz role (blocks 0..1023) + gu role (1024..2047) ----------
// rz: C=[y|x]@bRZ^T, 128x128 tile, BK=64 (identical to measured gemm_rz1). Epilogue
//     writes rxb/zb via agent-coherent stores, then flag[mb] += 1 (8 producers per mb).
// gu: accF=[y|rx]@bG^T, 64x128 tile (identical math to measured gemm_gu2), split:
//     K-half 0 reads yb (cast product, no dependency) -> runs concurrently with rz;
//     then spins (relaxed, failsafe-bounded) on flag[mb>>1]==8; K-half 1 stages rxb
//     via agent-coherent reg loads + ds_write (can't use global_load_lds: must
//     bypass consumer L2); epilogue reads zb coherent.
// Deadlock-free under any dispatch order: rz waits on nothing; gu waits only on rz.
// 32KB LDS -> 5 blocks/CU: early gu blocks ride the 5th slot during rz (extra TLP).
__global__ __launch_bounds__(256, 4) void gemm_rzgu(GArgs a) {
  __shared__ u16 smem[16384];  // 32 KB: rz uses all, gu uses first 24 KB
  const int tid = (int)threadIdx.x;
  const int lane = tid & 63;
  const int wave = tid >> 6;
  const int waveM = wave >> 1, waveN = wave & 1;
  const int wbyte = (tid & 192) * 16;
  const int lm = lane & 15, quad = lane >> 4;
  const int srow = tid >> 3;
  const int scol = (((tid & 7) ^ ((tid >> 3) & 7)) * 8);
  const int lswz = lm & 7;

  if (blockIdx.x < 1024) {
    // ================= rz role =================
    u16* sA = smem;
    u16* sB = smem + 8192;
    const int mb = (int)blockIdx.x & 127, nb = (int)blockIdx.x >> 7;  // mb fast
    const int rowStart = mb * 128, colStart = nb * 128;

    f32x4 acc[4][4] = {};

    for (int kq = 0; kq < 16; ++kq) {
      const int half = kq >> 3;
      const int k0 = (kq & 7) * 64;
      const u16* abase = half ? a.xb : a.yb;  // A = [y | x] along K
#pragma unroll
      for (int s = 0; s < 4; ++s) {
        async16(abase + (size_t)(rowStart + s * 32 + srow) * 512 + k0 + scol,
                (u16*)((char*)sA + s * 4096 + wbyte));
        async16(a.bRZ + (size_t)(colStart + s * 32 + srow) * 1024 + kq * 64 + scol,
                (u16*)((char*)sB + s * 4096 + wbyte));
      }
      __syncthreads();

#pragma unroll
      for (int kk = 0; kk < 2; ++kk) {
        bf16x8 aa[4], bw[4];
#pragma unroll
        for (int i = 0; i < 4; ++i)
          aa[i] = *(const bf16x8*)(sA + (waveM * 64 + i * 16 + lm) * 64 +
                                   ((kk * 4 + quad) ^ lswz) * 8);
#pragma unroll
        for (int j = 0; j < 4; ++j)
          bw[j] = *(const bf16x8*)(sB + (waveN * 64 + j * 16 + lm) * 64 +
                                   ((kk * 4 + quad) ^ lswz) * 8);
#pragma unroll
        for (int i = 0; i < 4; ++i)
#pragma unroll
          for (int j = 0; j < 4; ++j)
            acc[i][j] = __builtin_amdgcn_mfma_f32_16x16x32_bf16(aa[i], bw[j], acc[i][j], 0, 0, 0);
      }
      __syncthreads();
    }

    if (colStart < 512) {
      // R half: rx = bf16(sigmoid(acc) * x), agent-coherent stores
#pragma unroll
      for (int j = 0; j < 4; ++j) {
        const int e = colStart + waveN * 64 + j * 16 + lm;
#pragma unroll
        for (int i = 0; i < 4; ++i) {
          const int m0 = rowStart + waveM * 64 + i * 16 + quad * 4;
#pragma unroll
          for (int rg = 0; rg < 4; ++rg) {
            const size_t idx = (size_t)(m0 + rg) * 512 + e;
            const float r = sigmoidf_(acc[i][j][rg]);
            st_u16_coh(&a.rxb[idx], f2bf(r * bf2f(a.xb[idx])));
          }
        }
      }
    } else {
      // Z half: z = bf16(sigmoid(acc - bg)), agent-coherent stores
#pragma unroll
      for (int j = 0; j < 4; ++j) {
        const int e = colStart - 512 + waveN * 64 + j * 16 + lm;
        const float bgv = a.bg[e];
#pragma unroll
        for (int i = 0; i < 4; ++i) {
          const int m0 = rowStart + waveM * 64 + i * 16 + quad * 4;
#pragma unroll
          for (int rg = 0; rg < 4; ++rg) {
            const size_t idx = (size_t)(m0 + rg) * 512 + e;
            st_u16_coh(&a.zb[idx], f2bf(sigmoidf_(acc[i][j][rg] - bgv)));
          }
        }
      }
    }
    // Publish: drain this wave's coherent stores, join block, one flag add.
    asm volatile("s_waitcnt vmcnt(0)" ::: "memory");
    __syncthreads();  // implicit vmcnt(0) for all waves before s_barrier
    if (tid == 0)
      __hip_atomic_fetch_add(&a.flags[mb], 1u, __ATOMIC_RELAXED, __HIP_MEMORY_SCOPE_AGENT);
    return;
  }

  // ================= gu role =================
  {
    u16* sA = smem;          // 2 slabs x 4 KB = 8 KB
    u16* sB = smem + 4096;   // 4 slabs x 4 KB = 16 KB
    const int bid2 = (int)blockIdx.x - 1024;
    const int mb = bid2 & 255, nb = bid2 >> 8;  // mb fast
    const int rowStart = mb * 64, colStart = nb * 128;

    f32x4 acc[2][4] = {};

    // ---- K-half 0: A = yb (cast product, no dependency on rz) ----
    for (int kq = 0; kq < 8; ++kq) {
      const int k0 = kq * 64;
#pragma unroll
      for (int s = 0; s < 2; ++s)
        async16(a.yb + (size_t)(rowStart + s * 32 + srow) * 512 + k0 + scol,
                (u16*)((char*)sA + s * 4096 + wbyte));
#pragma unroll
      for (int s = 0; s < 4; ++s)
        async16(a.bG + (size_t)(colStart + s * 32 + srow) * 1024 + kq * 64 + scol,
                (u16*)((char*)sB + s * 4096 + wbyte));
      __syncthreads();

#pragma unroll
      for (int kk = 0; kk < 2; ++kk) {
        bf16x8 aa[2], bw[4];
#pragma unroll
        for (int i = 0; i < 2; ++i)
          aa[i] = *(const bf16x8*)(sA + (waveM * 32 + i * 16 + lm) * 64 +
                                   ((kk * 4 + quad) ^ lswz) * 8);
#pragma unroll
        for (int j = 0; j < 4; ++j)
          bw[j] = *(const bf16x8*)(sB + (waveN * 64 + j * 16 + lm) * 64 +
                                   ((kk * 4 + quad) ^ lswz) * 8);
#pragma unroll
        for (int i = 0; i < 2; ++i)
#pragma unroll
          for (int j = 0; j < 4; ++j)
            acc[i][j] = __builtin_amdgcn_mfma_f32_16x16x32_bf16(aa[i], bw[j], acc[i][j], 0, 0, 0);
      }
      __syncthreads();
    }

    // ---- wait for rxb/zb rows [rowStart, rowStart+64): rz mb = rowStart>>7, 8 producers ----
    if (tid == 0) {
      unsigned spins = 0;
      const int mf = mb >> 1;
      while (__hip_atomic_load(&a.flags[mf], __ATOMIC_RELAXED, __HIP_MEMORY_SCOPE_AGENT) < 8u) {
        __builtin_amdgcn_s_sleep(8);
        if (++spins > (1u << 18)) break;  // failsafe: fail numerics, never hang
      }
    }
    __syncthreads();
    asm volatile("" ::: "memory");
    __builtin_amdgcn_sched_barrier(0);

    // ---- K-half 1: A = rxb via agent-coherent reg loads + ds_write (bypass L2) ----
    for (int kq = 8; kq < 16; ++kq) {
      const int k0 = (kq & 7) * 64;
#pragma unroll
      for (int s = 0; s < 2; ++s) {
        const u64* src = (const u64*)(a.rxb_c + (size_t)(rowStart + s * 32 + srow) * 512 + k0 + scol);
        u64 lo = ld_u64_coh(src);
        u64 hi = ld_u64_coh(src + 1);
        u64* dst = (u64*)((char*)sA + s * 4096 + wbyte + (lane << 4));
        dst[0] = lo;
        dst[1] = hi;
      }
#pragma unroll
      for (int s = 0; s < 4; ++s)
        async16(a.bG + (size_t)(colStart + s * 32 + srow) * 1024 + kq * 64 + scol,
                (u16*)((char*)sB + s * 4096 + wbyte));
      __syncthreads();

#pragma unroll
      for (int kk = 0; kk < 2; ++kk) {
        bf16x8 aa[2], bw[4];
#pragma unroll
        for (int i = 0; i < 2; ++i)
          aa[i] = *(const bf16x8*)(sA + (waveM * 32 + i * 16 + lm) * 64 +
                                   ((kk * 4 + quad) ^ lswz) * 8);
#pragma unroll
        for (int j = 0; j < 4; ++j)
          bw[j] = *(const bf16x8*)(sB + (waveN * 64 + j * 16 + lm) * 64 +
                                   ((kk * 4 + quad) ^ lswz) * 8);
#pragma unroll
        for (int i = 0; i < 2; ++i)
#pragma unroll
          for (int j = 0; j < 4; ++j)
            acc[i][j] = __builtin_amdgcn_mfma_f32_16x16x32_bf16(aa[i], bw[j], acc[i][j], 0, 0, 0);
      }
      __syncthreads();
    }

    // epilogue: out = (1-z)x + z*tanh(accF); z read agent-coherent
#pragma unroll
    for (int j = 0; j < 4; ++j) {
      const int e = colStart + waveN * 64 + j * 16 + lm;
#pragma unroll
      for (int i = 0; i < 2; ++i) {
        const int m0 = rowStart + waveM * 32 + i * 16 + quad * 4;
#pragma unroll
        for (int rg = 0; rg < 4; ++rg) {
          const size_t idx = (size_t)(m0 + rg) * 512 + e;
          const float pre = acc[i][j][rg];
          const float ex = __expf(-2.f * pre);
          const float h = (1.f - ex) / (1.f + ex);  // tanh
          const float z = bf2f(ld_u16_coh(&a.zb_c[idx]));
          const float xv = bf2f(a.xb[idx]);
          a.out[idx] = (1.f - z) * xv + z * h;
        }
      }
    }
  }
}

// ---------- launch ----------
extern "C" void kernel_launch(void* const* d_in, const int* in_sizes, int n_in,
                              void* d_out, int out_size, void* d_ws, size_t ws_size,
                              hipStream_t stream) {
  const float* x  = (const float*)d_in[0];
  const float* y  = (const float*)d_in[1];
  const float* Wr = (const float*)d_in[2];
  const float* Ur = (const float*)d_in[3];
  const float* Wz = (const float*)d_in[4];
  const float* Uz = (const float*)d_in[5];
  const float* Wg = (const float*)d_in[6];
  const float* Ug = (const float*)d_in[7];
  const float* bg = (const float*)d_in[8];

  // ws layout (bytes): yb 16M | xb 16M | rxb 16M | zb 16M | bRZ 2M | bG 1M | flags 512B
  char* ws = (char*)d_ws;
  u16* yb  = (u16*)(ws);
  u16* xb  = (u16*)(ws + 16777216);
  u16* rxb = (u16*)(ws + 2 * 16777216);
  u16* zb  = (u16*)(ws + 3 * 16777216);
  u16* bRZ = (u16*)(ws + 4 * 16777216);
  u16* bG  = (u16*)(ws + 4 * 16777216 + 2097152);
  unsigned* flags = (unsigned*)(ws + 4 * 16777216 + 2097152 + 1048576);

  GArgs ga;
  ga.yb = yb; ga.xb = xb; ga.bRZ = bRZ; ga.bG = bG; ga.bg = bg;
  ga.rxb = rxb; ga.zb = zb; ga.rxb_c = rxb; ga.zb_c = zb;
  ga.out = (float*)d_out;
  ga.flags = flags;

  // Captured into the graph -> flags re-zeroed on every replay.
  hipMemsetAsync(flags, 0, 512, stream);
  cast_all2<<<2048, 256, 0, stream>>>(y, x, Wr, Ur, Wz, Uz, Wg, Ug, yb, xb, bRZ, bG);
  gemm_rzgu<<<2048, 256, 0, stream>>>(ga);
}

// Round 8
// 230.221 us; speedup vs baseline: 2.6572x; 1.0161x over previous
//
#include <hip/hip_runtime.h>
#include <stdint.h>

typedef unsigned short u16;
typedef unsigned long long u64;
typedef __attribute__((ext_vector_type(8))) __bf16 bf16x8;
typedef __attribute__((ext_vector_type(4))) float f32x4;

#define Dn 512
#define Mn 16384  // T*B rows

// ---------- helpers ----------

__device__ __forceinline__ u16 f2bf(float f) {
  unsigned u = __float_as_uint(f);
  u += 0x7fffu + ((u >> 16) & 1u);
  return (u16)(u >> 16);
}

__device__ __forceinline__ float bf2f(u16 b) {
  return __uint_as_float(((unsigned)b) << 16);
}

__device__ __forceinline__ void async16(const u16* g, u16* l) {
  // global -> LDS direct copy, 16 B per lane. LDS dest = wave-uniform base + lane*16.
  __builtin_amdgcn_global_load_lds(
      (const __attribute__((address_space(1))) unsigned int*)g,
      (__attribute__((address_space(3))) unsigned int*)l, 16, 0, 0);
}

__device__ __forceinline__ float sigmoidf_(float v) {
  return 1.f / (1.f + __expf(-v));
}

// Agent-scope relaxed (write-through) stores: publish producer data at the LLC so
// correctness does NOT depend on workgroup->XCD mapping (G16). No buffer_inv/wbl2
// (round-6 lesson). Consumers use PLAIN loads (round-7 lesson: coherent loads pay
// LLC latency per element) -- safe because every consumer address is first-touched
// AFTER the producer flag within this kernel instance, and kernel-start acquire
// invalidates stale lines across graph replays.
__device__ __forceinline__ void st_u64_coh(u64* p, u64 v) {
  __hip_atomic_store(p, v, __ATOMIC_RELAXED, __HIP_MEMORY_SCOPE_AGENT);
}
__device__ __forceinline__ void st_u16_coh(u16* p, u16 v) {
  __hip_atomic_store(p, v, __ATOMIC_RELAXED, __HIP_MEMORY_SCOPE_AGENT);
}

__device__ __forceinline__ u64 pack4bf(float4 v) {
  u64 r = (u64)f2bf(v.x) | ((u64)f2bf(v.y) << 16) |
          ((u64)f2bf(v.z) << 32) | ((u64)f2bf(v.w) << 48);
  return r;
}

// ---------- weights cast kernel (tiny; kernel boundary = unconditional coherence) ----------
// grid 1536: 6 weights x 256 blocks; concat layouts:
//   bRZ (1024 x 1024 bf16): rows 0-511 = [Wr | Ur], rows 512-1023 = [Wz | Uz]
//   bG  ( 512 x 1024 bf16): rows 0-511 = [Wg | Ug]
__global__ void cast_w(const float* w0, const float* w1, const float* w2,
                       const float* w3, const float* w4, const float* w5,
                       u16* __restrict__ bRZ, u16* __restrict__ bG) {
  const int b = (int)blockIdx.x;
  const int t = (int)threadIdx.x;
  const int wi = b >> 8;  // 0..5 : Wr,Ur,Wz,Uz,Wg,Ug
  const int bb = b & 255;
  const float* src = wi == 0 ? w0 : wi == 1 ? w1 : wi == 2 ? w2
                   : wi == 3 ? w3 : wi == 4 ? w4 : w5;
  const int i4 = bb * 256 + t;        // float4 index within 512x512 weight
  const int e  = i4 >> 7;             // output row 0..511
  const int c4 = i4 & 127;            // float4 col within 512
  float4 v = ((const float4*)src)[i4];
  ushort4 o;
  o.x = f2bf(v.x); o.y = f2bf(v.y); o.z = f2bf(v.z); o.w = f2bf(v.w);
  ushort4* base = (wi >= 4) ? (ushort4*)bG : (ushort4*)bRZ;
  const int row = e + ((wi == 2 || wi == 3) ? 512 : 0);
  const int off = row * 256 + c4 + ((wi & 1) ? 128 : 0);  // 256 ushort4 per 1024-col row
  base[off] = o;
}

struct GArgs {
  const float *yf, *xf, *bg;
  u16 *yb, *xb, *rxb, *zb;
  const u16 *bRZ, *bG;
  float* out;
  unsigned *cflag, *rflag;  // 128 each; target count 8 (all nb of an mb)
};

// ---------- fused kernel: castA -> flag -> rz -> flag -> gu(half0 | wait | half1) ----------
// Grid 1024 = 128 mb x 8 nb (mb fast), 4 blocks/CU resident. ALL inter-block deps are
// mb-local (8 sibling blocks): y/x cast rows, rxb, zb. Producers publish write-through;
// consumers plain-load after per-mb flag. gu K-half-0 (yb only) runs before the rz wait
// to hide sibling jitter. Phase bodies B/C/D byte-match measured gemm_rz1 / gemm_gu2.
__global__ __launch_bounds__(256, 4) void fused_rzgu(GArgs a) {
  __shared__ u16 smem[16384];  // 32 KB: rz uses all, gu uses first 24 KB
  const int tid = (int)threadIdx.x;
  const int lane = tid & 63;
  const int wave = tid >> 6;
  const int waveM = wave >> 1, waveN = wave & 1;
  const int wbyte = (tid & 192) * 16;
  const int lm = lane & 15, quad = lane >> 4;
  const int srow = tid >> 3;
  const int scol = (((tid & 7) ^ ((tid >> 3) & 7)) * 8);
  const int lswz = lm & 7;
  const int mb = (int)blockIdx.x & 127, nb = (int)blockIdx.x >> 7;  // mb fast -> same XCD
  const int rowStart = mb * 128, colStart = nb * 128;

  // ================= phase A: cast 16 rows of y and x (rows mb*128 + nb*16 ..+16) ====
  {
    const int r0 = rowStart + nb * 16;
#pragma unroll
    for (int k = tid; k < 2048; k += 256) {
      const int gi = (r0 + (k >> 7)) * 128 + (k & 127);
      st_u64_coh((u64*)a.yb + gi, pack4bf(((const float4*)a.yf)[gi]));
      st_u64_coh((u64*)a.xb + gi, pack4bf(((const float4*)a.xf)[gi]));
    }
  }
  asm volatile("s_waitcnt vmcnt(0)" ::: "memory");
  __syncthreads();
  if (tid == 0) {
    __hip_atomic_fetch_add(&a.cflag[mb], 1u, __ATOMIC_RELAXED, __HIP_MEMORY_SCOPE_AGENT);
    unsigned spins = 0;
    while (__hip_atomic_load(&a.cflag[mb], __ATOMIC_RELAXED, __HIP_MEMORY_SCOPE_AGENT) < 8u) {
      __builtin_amdgcn_s_sleep(4);
      if (++spins > (1u << 20)) break;  // failsafe: wrong numerics, never a hang
    }
  }
  __syncthreads();
  __builtin_amdgcn_sched_barrier(0);

  // ================= phase B: rz  C=[y|x]@bRZ^T, 128x128 tile (== measured gemm_rz1) ==
  {
    u16* sA = smem;
    u16* sB = smem + 8192;

    f32x4 acc[4][4] = {};

    for (int kq = 0; kq < 16; ++kq) {
      const int half = kq >> 3;
      const int k0 = (kq & 7) * 64;
      const u16* abase = half ? a.xb : a.yb;  // A = [y | x] along K
#pragma unroll
      for (int s = 0; s < 4; ++s) {
        async16(abase + (size_t)(rowStart + s * 32 + srow) * 512 + k0 + scol,
                (u16*)((char*)sA + s * 4096 + wbyte));
        async16(a.bRZ + (size_t)(colStart + s * 32 + srow) * 1024 + kq * 64 + scol,
                (u16*)((char*)sB + s * 4096 + wbyte));
      }
      __syncthreads();

#pragma unroll
      for (int kk = 0; kk < 2; ++kk) {
        bf16x8 aa[4], bw[4];
#pragma unroll
        for (int i = 0; i < 4; ++i)
          aa[i] = *(const bf16x8*)(sA + (waveM * 64 + i * 16 + lm) * 64 +
                                   ((kk * 4 + quad) ^ lswz) * 8);
#pragma unroll
        for (int j = 0; j < 4; ++j)
          bw[j] = *(const bf16x8*)(sB + (waveN * 64 + j * 16 + lm) * 64 +
                                   ((kk * 4 + quad) ^ lswz) * 8);
#pragma unroll
        for (int i = 0; i < 4; ++i)
#pragma unroll
          for (int j = 0; j < 4; ++j)
            acc[i][j] = __builtin_amdgcn_mfma_f32_16x16x32_bf16(aa[i], bw[j], acc[i][j], 0, 0, 0);
      }
      __syncthreads();
    }

    if (colStart < 512) {
      // R half: rx = bf16(sigmoid(acc) * x), write-through
#pragma unroll
      for (int j = 0; j < 4; ++j) {
        const int e = colStart + waveN * 64 + j * 16 + lm;
#pragma unroll
        for (int i = 0; i < 4; ++i) {
          const int m0 = rowStart + waveM * 64 + i * 16 + quad * 4;
#pragma unroll
          for (int rg = 0; rg < 4; ++rg) {
            const size_t idx = (size_t)(m0 + rg) * 512 + e;
            const float r = sigmoidf_(acc[i][j][rg]);
            st_u16_coh(&a.rxb[idx], f2bf(r * bf2f(a.xb[idx])));
          }
        }
      }
    } else {
      // Z half: z = bf16(sigmoid(acc - bg)), write-through
#pragma unroll
      for (int j = 0; j < 4; ++j) {
        const int e = colStart - 512 + waveN * 64 + j * 16 + lm;
        const float bgv = a.bg[e];
#pragma unroll
        for (int i = 0; i < 4; ++i) {
          const int m0 = rowStart + waveM * 64 + i * 16 + quad * 4;
#pragma unroll
          for (int rg = 0; rg < 4; ++rg) {
            const size_t idx = (size_t)(m0 + rg) * 512 + e;
            st_u16_coh(&a.zb[idx], f2bf(sigmoidf_(acc[i][j][rg] - bgv)));
          }
        }
      }
    }
  }
  asm volatile("s_waitcnt vmcnt(0)" ::: "memory");
  __syncthreads();
  if (tid == 0)
    __hip_atomic_fetch_add(&a.rflag[mb], 1u, __ATOMIC_RELAXED, __HIP_MEMORY_SCOPE_AGENT);

  // ================= phase C/D: gu  accF=[y|rx]@bG^T, 64x128 tile (== gemm_gu2) =======
  // This block's gu tile: rows mb*128+(nb&1)*64 (subset of mb's rows), cols (nb>>2..)
  {
    u16* sA = smem;          // 2 slabs x 4 KB
    u16* sB = smem + 4096;   // 4 slabs x 4 KB (u16 offset 4096 = byte 8192)
    const int rowG = rowStart + (nb & 1) * 64;
    const int colG = (nb >> 1) * 128;

    f32x4 acc[2][4] = {};

    // ---- K-half 0: A = yb (cast-complete; no rz dependency) -- hides sibling jitter
    for (int kq = 0; kq < 8; ++kq) {
      const int k0 = kq * 64;
#pragma unroll
      for (int s = 0; s < 2; ++s)
        async16(a.yb + (size_t)(rowG + s * 32 + srow) * 512 + k0 + scol,
                (u16*)((char*)sA + s * 4096 + wbyte));
#pragma unroll
      for (int s = 0; s < 4; ++s)
        async16(a.bG + (size_t)(colG + s * 32 + srow) * 1024 + kq * 64 + scol,
                (u16*)((char*)sB + s * 4096 + wbyte));
      __syncthreads();

#pragma unroll
      for (int kk = 0; kk < 2; ++kk) {
        bf16x8 aa[2], bw[4];
#pragma unroll
        for (int i = 0; i < 2; ++i)
          aa[i] = *(const bf16x8*)(sA + (waveM * 32 + i * 16 + lm) * 64 +
                                   ((kk * 4 + quad) ^ lswz) * 8);
#pragma unroll
        for (int j = 0; j < 4; ++j)
          bw[j] = *(const bf16x8*)(sB + (waveN * 64 + j * 16 + lm) * 64 +
                                   ((kk * 4 + quad) ^ lswz) * 8);
#pragma unroll
        for (int i = 0; i < 2; ++i)
#pragma unroll
          for (int j = 0; j < 4; ++j)
            acc[i][j] = __builtin_amdgcn_mfma_f32_16x16x32_bf16(aa[i], bw[j], acc[i][j], 0, 0, 0);
      }
      __syncthreads();
    }

    // ---- wait for the 8 mb-sibling rz blocks (usually already done) ----
    if (tid == 0) {
      unsigned spins = 0;
      while (__hip_atomic_load(&a.rflag[mb], __ATOMIC_RELAXED, __HIP_MEMORY_SCOPE_AGENT) < 8u) {
        __builtin_amdgcn_s_sleep(4);
        if (++spins > (1u << 20)) break;  // failsafe
      }
    }
    __syncthreads();
    __builtin_amdgcn_sched_barrier(0);

    // ---- K-half 1: A = rxb via PLAIN global_load_lds (first touch after flag) ----
    for (int kq = 8; kq < 16; ++kq) {
      const int k0 = (kq & 7) * 64;
#pragma unroll
      for (int s = 0; s < 2; ++s)
        async16(a.rxb + (size_t)(rowG + s * 32 + srow) * 512 + k0 + scol,
                (u16*)((char*)sA + s * 4096 + wbyte));
#pragma unroll
      for (int s = 0; s < 4; ++s)
        async16(a.bG + (size_t)(colG + s * 32 + srow) * 1024 + kq * 64 + scol,
                (u16*)((char*)sB + s * 4096 + wbyte));
      __syncthreads();

#pragma unroll
      for (int kk = 0; kk < 2; ++kk) {
        bf16x8 aa[2], bw[4];
#pragma unroll
        for (int i = 0; i < 2; ++i)
          aa[i] = *(const bf16x8*)(sA + (waveM * 32 + i * 16 + lm) * 64 +
                                   ((kk * 4 + quad) ^ lswz) * 8);
#pragma unroll
        for (int j = 0; j < 4; ++j)
          bw[j] = *(const bf16x8*)(sB + (waveN * 64 + j * 16 + lm) * 64 +
                                   ((kk * 4 + quad) ^ lswz) * 8);
#pragma unroll
        for (int i = 0; i < 2; ++i)
#pragma unroll
          for (int j = 0; j < 4; ++j)
            acc[i][j] = __builtin_amdgcn_mfma_f32_16x16x32_bf16(aa[i], bw[j], acc[i][j], 0, 0, 0);
      }
      __syncthreads();
    }

    // epilogue: out = (1-z)x + z*tanh(accF); zb/xb PLAIN loads
#pragma unroll
    for (int j = 0; j < 4; ++j) {
      const int e = colG + waveN * 64 + j * 16 + lm;
#pragma unroll
      for (int i = 0; i < 2; ++i) {
        const int m0 = rowG + waveM * 32 + i * 16 + quad * 4;
#pragma unroll
        for (int rg = 0; rg < 4; ++rg) {
          const size_t idx = (size_t)(m0 + rg) * 512 + e;
          const float pre = acc[i][j][rg];
          const float ex = __expf(-2.f * pre);
          const float h = (1.f - ex) / (1.f + ex);  // tanh
          const float z = bf2f(a.zb[idx]);
          const float xv = bf2f(a.xb[idx]);
          a.out[idx] = (1.f - z) * xv + z * h;
        }
      }
    }
  }
}

// ---------- launch ----------
extern "C" void kernel_launch(void* const* d_in, const int* in_sizes, int n_in,
                              void* d_out, int out_size, void* d_ws, size_t ws_size,
                              hipStream_t stream) {
  const float* x  = (const float*)d_in[0];
  const float* y  = (const float*)d_in[1];
  const float* Wr = (const float*)d_in[2];
  const float* Ur = (const float*)d_in[3];
  const float* Wz = (const float*)d_in[4];
  const float* Uz = (const float*)d_in[5];
  const float* Wg = (const float*)d_in[6];
  const float* Ug = (const float*)d_in[7];
  const float* bg = (const float*)d_in[8];

  // ws layout (bytes): yb 16M | xb 16M | rxb 16M | zb 16M | bRZ 2M | bG 1M | flags 1K
  char* ws = (char*)d_ws;
  u16* yb  = (u16*)(ws);
  u16* xb  = (u16*)(ws + 16777216);
  u16* rxb = (u16*)(ws + 2 * 16777216);
  u16* zb  = (u16*)(ws + 3 * 16777216);
  u16* bRZ = (u16*)(ws + 4 * 16777216);
  u16* bG  = (u16*)(ws + 4 * 16777216 + 2097152);
  char* flags = ws + 4 * 16777216 + 2097152 + 1048576;

  GArgs ga;
  ga.yf = y; ga.xf = x; ga.bg = bg;
  ga.yb = yb; ga.xb = xb; ga.rxb = rxb; ga.zb = zb;
  ga.bRZ = bRZ; ga.bG = bG;
  ga.out = (float*)d_out;
  ga.cflag = (unsigned*)flags;
  ga.rflag = (unsigned*)(flags + 512);

  // Captured into the graph -> flags re-zeroed on every replay.
  hipMemsetAsync(flags, 0, 1024, stream);
  cast_w<<<1536, 256, 0, stream>>>(Wr, Ur, Wz, Uz, Wg, Ug, bRZ, bG);
  fused_rzgu<<<1024, 256, 0, stream>>>(ga);
}